// Round 1
// baseline (285.084 us; speedup 1.0000x reference)
//
#include <hip/hip_runtime.h>

#define BB 512
#define CC 6
#define TT 77
#define DD 512
#define LIMG 193

// One block per batch element b. 512 threads = 8 waves.
//   col = tid & 127 : which float4 chunk of D (128 chunks of 4 floats)
//   q   = tid >> 7  : T-stripe quarter (t = q, q+4, q+8, ...)
// local_text partials combined via LDS; mask staged in LDS (lane-broadcast reads).
__global__ __launch_bounds__(512) void clip_fused(
    const float* __restrict__ img,
    const float* __restrict__ txt,
    const float* __restrict__ ls,
    const int* __restrict__ cap,
    const int* __restrict__ mask,
    float* __restrict__ out)
{
    const int b   = blockIdx.x;
    const int tid = threadIdx.x;
    const int col = tid & 127;
    const int q   = tid >> 7;

    __shared__ float m[CC * TT];        // 1848 B
    __shared__ int   wred[8];
    __shared__ float4 part[4][CC][128]; // 48 KiB

    // ---- stage mask as float in LDS ----
    const int* mrow = mask + (size_t)b * (CC * TT);
    for (int i = tid; i < CC * TT; i += 512) m[i] = (float)mrow[i];

    // ---- argmax(captions[b,:]) with first-index tie-break ----
    // key = (value << 8) | (255 - t): max over keys -> max value, smallest t wins ties.
    const int* crow = cap + (size_t)b * TT;
    int key = -1;
    if (tid < TT) key = (crow[tid] << 8) | (255 - tid);
    #pragma unroll
    for (int off = 32; off; off >>= 1) key = max(key, __shfl_down(key, off));
    if ((tid & 63) == 0) wred[tid >> 6] = key;
    __syncthreads();

    int kmax = wred[0];
    #pragma unroll
    for (int w = 1; w < 8; w++) kmax = max(kmax, wred[w]);
    const int eot = 255 - (kmax & 255);

    const float4* trow = (const float4*)(txt + (size_t)b * (TT * DD));

    // ---- global_text (q==0) and global_image (q==1) copies, issued early ----
    if (q == 0) {
        float4 g = trow[(size_t)eot * 128 + col];
        ((float4*)out)[(size_t)b * 128 + col] = g;
    } else if (q == 1) {
        const float4* irow = (const float4*)(img + (size_t)b * (LIMG * DD));
        ((float4*)(out + (size_t)BB * DD))[(size_t)b * 128 + col] = irow[col];
    }

    // ---- masked T-sum, quarter-strided partials ----
    float4 acc[CC];
    #pragma unroll
    for (int c = 0; c < CC; c++) acc[c] = make_float4(0.f, 0.f, 0.f, 0.f);

    #pragma unroll 5
    for (int t = q; t < TT; t += 4) {
        float4 v = trow[(size_t)t * 128 + col];
        #pragma unroll
        for (int c = 0; c < CC; c++) {
            float w = m[c * TT + t];   // uniform per wave -> LDS broadcast
            acc[c].x += w * v.x;
            acc[c].y += w * v.y;
            acc[c].z += w * v.z;
            acc[c].w += w * v.w;
        }
    }
    #pragma unroll
    for (int c = 0; c < CC; c++) part[q][c][col] = acc[c];
    __syncthreads();

    // ---- combine quarters, scale by 1/T, write local_text ----
    float4* out_lt = (float4*)(out + 2 * (size_t)BB * DD);
    const float inv = 1.0f / (float)TT;
    for (int i = tid; i < CC * 128; i += 512) {
        int c  = i >> 7;
        int cc = i & 127;
        float4 s0 = part[0][c][cc];
        float4 s1 = part[1][c][cc];
        float4 s2 = part[2][c][cc];
        float4 s3 = part[3][c][cc];
        float4 r;
        r.x = (s0.x + s1.x + s2.x + s3.x) * inv;
        r.y = (s0.y + s1.y + s2.y + s3.y) * inv;
        r.z = (s0.z + s1.z + s2.z + s3.z) * inv;
        r.w = (s0.w + s1.w + s2.w + s3.w) * inv;
        out_lt[((size_t)b * CC + c) * 128 + cc] = r;
    }

    // ---- logit_scale passthrough ----
    if (b == 0 && tid == 0)
        out[(size_t)2 * BB * DD + (size_t)BB * CC * DD] = ls[0];
}

extern "C" void kernel_launch(void* const* d_in, const int* in_sizes, int n_in,
                              void* d_out, int out_size, void* d_ws, size_t ws_size,
                              hipStream_t stream) {
    const float* img  = (const float*)d_in[0];  // (B, LI, D) f32
    const float* txt  = (const float*)d_in[1];  // (B, T, D)  f32
    const float* ls   = (const float*)d_in[2];  // (1,)       f32
    const int*   cap  = (const int*)d_in[3];    // (B, T)     i32
    const int*   mask = (const int*)d_in[4];    // (B, C, T)  i32
    float* out = (float*)d_out;

    clip_fused<<<dim3(BB), dim3(512), 0, stream>>>(img, txt, ls, cap, mask, out);
}